// Round 2
// baseline (44.956 us; speedup 1.0000x reference)
//
#include <hip/hip_runtime.h>

// ProximityAwareLoss3Class, B=32, S=65536, C=3 — single fused kernel.
//
// All serial structure reduces to per-sequence last-event max-scans (fwd) and
// next-event min-scans (bwd) over 10 channels:
//   fwd: lastT1,lastT2,lastP1,lastP2,lastVP1,lastVP2   (tm=(lastT2>lastT1), pm=(lastVP2>lastVP1) exclusive)
//   bwd: nextT1,nextT2,nextP1,nextP2                   (inclusive)
// Distances clamp at 255 (all proximity factors saturate by d>=25).
//
// One pass: each block handles one 4096-elem chunk (512 blocks = 32 seq x 16
// chunks), keeps CE + packed pred/label in registers, publishes its 10-channel
// chunk summary via device-scope release flag, spins for its sequence's 16
// summaries (all blocks co-resident: publish-before-spin + launch_bounds(256,2)
// guarantees >=2 blocks/CU -> 512 resident), then finishes locally.
// Final mean via last-block-done counter (deterministic fixed-order reduce).
// Flags+counter cleared each call by a hipMemsetAsync node (ws is not
// re-poisoned between graph replays, so stale flags must be wiped).

#define S_LEN 65536
#define BATCH 32
#define CHUNK 4096
#define NTHREADS 256
#define PT 16
#define CPS 16              // chunks per sequence
#define NCH 512             // total chunks = BATCH * CPS
#define BIGI 0x3FFFFFFF

// ws layout (bytes)
#define WS_FLAGS 0          // NCH * 4 = 2048
#define WS_CTR   2048       // 4
#define WS_CLEAR 2112       // memset range covering flags + ctr
#define WS_SUMS  2112       // NCH * 10 * 4 = 20480
#define WS_PART  22592      // NCH * 2 * 8 = 8192 (8-aligned)

__global__ __launch_bounds__(NTHREADS, 2) void fused_loss(
    const float* __restrict__ logits, const int* __restrict__ labels,
    int* __restrict__ flags, int* __restrict__ ctr,
    int* __restrict__ sums, double* __restrict__ partials,
    float* __restrict__ out)
{
    const int chunkId = blockIdx.x;
    const int seq = chunkId >> 4;
    const int cs  = chunkId & (CPS - 1);
    const int tid = threadIdx.x;
    const int lane = tid & 63;
    const int wid  = tid >> 6;
    const int posBase = cs * CHUNK + tid * PT;          // sequence-local
    const long long e0 = (long long)seq * S_LEN + posBase;

    // ---------------- phase 1: load once, pred + CE, pack ----------------
    float ce[PT];
    unsigned long long code = 0ull;   // 4 bits/elem: pred(2) | labcode(2); labcode 3 = ignore
    {
        const float4* fp = (const float4*)(logits + 3 * e0);
        const int4*   lp = (const int4*)(labels + e0);
        #pragma unroll
        for (int h = 0; h < 2; ++h) {
            float f[24];
            #pragma unroll
            for (int i = 0; i < 6; ++i) {
                float4 v = fp[6 * h + i];
                f[4*i+0]=v.x; f[4*i+1]=v.y; f[4*i+2]=v.z; f[4*i+3]=v.w;
            }
            int lb[8];
            { int4 a = lp[2*h], b = lp[2*h+1];
              lb[0]=a.x; lb[1]=a.y; lb[2]=a.z; lb[3]=a.w;
              lb[4]=b.x; lb[5]=b.y; lb[6]=b.z; lb[7]=b.w; }
            #pragma unroll
            for (int j8 = 0; j8 < 8; ++j8) {
                const int j = h * 8 + j8;
                const float l0 = f[3*j8], l1 = f[3*j8+1], l2 = f[3*j8+2];
                int p = 0; float bst = l0;
                if (l1 > bst) { p = 1; bst = l1; }
                if (l2 > bst) { p = 2; }
                const int l  = lb[j8];
                const int lc = (l < 0) ? 3 : l;
                code |= ((unsigned long long)(p | (lc << 2))) << (4 * j);
                float c = 0.0f;
                if (lc != 3) {
                    const float mx  = fmaxf(l0, fmaxf(l1, l2));
                    const float lse = mx + __logf(__expf(l0-mx) + __expf(l1-mx) + __expf(l2-mx));
                    const float ly  = (lc == 0) ? l0 : ((lc == 1) ? l1 : l2);
                    const float w   = (lc == 0) ? 1.0f : 30.0f;
                    c = -(ly - lse) * w;
                }
                ce[j] = c;
            }
        }
    }

    // ---------------- thread-local scan summaries ----------------
    int iF[6] = {-1,-1,-1,-1,-1,-1};
    int iB[4] = {BIGI,BIGI,BIGI,BIGI};
    #pragma unroll
    for (int j = 0; j < PT; ++j) {
        const int nib = (int)((code >> (4*j)) & 0xFull);
        const int p = nib & 3, lc = (nib >> 2) & 3;
        const int pos = posBase + j;
        if (lc == 1) iF[0] = pos;
        if (lc == 2) iF[1] = pos;
        if (p  == 1) iF[2] = pos;
        if (p  == 2) iF[3] = pos;
        const bool valid = lc != 3;
        if (valid && p == 1) iF[4] = pos;
        if (valid && p == 2) iF[5] = pos;
    }
    #pragma unroll
    for (int j = PT - 1; j >= 0; --j) {    // descending -> keeps smallest pos
        const int nib = (int)((code >> (4*j)) & 0xFull);
        const int p = nib & 3, lc = (nib >> 2) & 3;
        const int pos = posBase + j;
        if (lc == 1) iB[0] = pos;
        if (lc == 2) iB[1] = pos;
        if (p  == 1) iB[2] = pos;
        if (p  == 2) iB[3] = pos;
    }

    // ---------------- wave inclusive scans (shuffle, no LDS) ----------------
    #pragma unroll
    for (int i = 0; i < 6; ++i) {
        int v = iF[i];
        #pragma unroll
        for (int o = 1; o < 64; o <<= 1) {
            int t = __shfl_up(v, o);
            if (lane >= o) v = max(v, t);
        }
        iF[i] = v;
    }
    #pragma unroll
    for (int i = 0; i < 4; ++i) {
        int v = iB[i];
        #pragma unroll
        for (int o = 1; o < 64; o <<= 1) {
            int t = __shfl_down(v, o);
            if (lane + o < 64) v = min(v, t);
        }
        iB[i] = v;
    }

    __shared__ int wtF[6][4];
    __shared__ int wtB[4][4];
    if (lane == 63) {
        #pragma unroll
        for (int i = 0; i < 6; ++i) wtF[i][wid] = iF[i];
    }
    if (lane == 0) {
        #pragma unroll
        for (int i = 0; i < 4; ++i) wtB[i][wid] = iB[i];
    }
    __syncthreads();

    // ---------------- publish own chunk summary (before any spin!) ----------------
    if (tid == 0) {
        int s[10];
        #pragma unroll
        for (int i = 0; i < 6; ++i)
            s[i] = max(max(wtF[i][0], wtF[i][1]), max(wtF[i][2], wtF[i][3]));
        #pragma unroll
        for (int i = 0; i < 4; ++i)
            s[6+i] = min(min(wtB[i][0], wtB[i][1]), min(wtB[i][2], wtB[i][3]));
        int* dst = sums + chunkId * 10;
        #pragma unroll
        for (int i = 0; i < 10; ++i)
            __hip_atomic_store(dst + i, s[i], __ATOMIC_RELAXED, __HIP_MEMORY_SCOPE_AGENT);
        __hip_atomic_store(&flags[chunkId], 1, __ATOMIC_RELEASE, __HIP_MEMORY_SCOPE_AGENT);
    }

    // ---------------- cross-chunk prologue: spin + prefix ----------------
    __shared__ int ls[CPS][10];
    __shared__ int pro[14];      // inL[6], inN[4], any[4]
    if (tid < CPS) {
        const int c = seq * CPS + tid;
        while (__hip_atomic_load(&flags[c], __ATOMIC_ACQUIRE, __HIP_MEMORY_SCOPE_AGENT) == 0) {
            __builtin_amdgcn_s_sleep(1);
        }
        const int* src = sums + c * 10;
        #pragma unroll
        for (int i = 0; i < 10; ++i)
            ls[tid][i] = __hip_atomic_load(src + i, __ATOMIC_RELAXED, __HIP_MEMORY_SCOPE_AGENT);
    }
    __syncthreads();
    if (tid == 0) {
        int inL[6] = {-1,-1,-1,-1,-1,-1};
        int inN[4] = {BIGI,BIGI,BIGI,BIGI};
        for (int k = 0; k < cs; ++k) {
            #pragma unroll
            for (int i = 0; i < 6; ++i) inL[i] = max(inL[i], ls[k][i]);
        }
        for (int k = cs + 1; k < CPS; ++k) {
            #pragma unroll
            for (int i = 0; i < 4; ++i) inN[i] = min(inN[i], ls[k][6+i]);
        }
        #pragma unroll
        for (int i = 0; i < 6; ++i) pro[i] = inL[i];
        #pragma unroll
        for (int i = 0; i < 4; ++i) pro[6+i] = inN[i];
        #pragma unroll
        for (int i = 0; i < 4; ++i) {
            int r = -1;
            for (int k = 0; k < CPS; ++k) r = max(r, ls[k][i]);
            pro[10+i] = (r >= 0) ? 1 : 0;
        }
    }
    __syncthreads();

    // ---------------- per-thread exclusive carries ----------------
    int exF[6], exB[4];
    #pragma unroll
    for (int i = 0; i < 6; ++i) {
        int carry = pro[i];
        #pragma unroll
        for (int w = 0; w < 3; ++w)
            if (w < wid) carry = max(carry, wtF[i][w]);
        const int t = __shfl_up(iF[i], 1);
        exF[i] = (lane > 0) ? max(carry, t) : carry;
    }
    #pragma unroll
    for (int i = 0; i < 4; ++i) {
        int carry = pro[6+i];
        #pragma unroll
        for (int w = 1; w < 4; ++w)
            if (w > wid) carry = min(carry, wtB[i][w]);
        const int t = __shfl_down(iB[i], 1);
        exB[i] = (lane < 63) ? min(carry, t) : carry;
    }

    // ---------------- backward walk: packed next-distances ----------------
    unsigned nd[PT];
    {
        int n1 = exB[0], n2 = exB[1], n3 = exB[2], n4 = exB[3];
        #pragma unroll
        for (int j = PT - 1; j >= 0; --j) {
            const int nib = (int)((code >> (4*j)) & 0xFull);
            const int p = nib & 3, lc = (nib >> 2) & 3;
            const int pos = posBase + j;
            if (lc == 1) n1 = pos;
            if (lc == 2) n2 = pos;
            if (p  == 1) n3 = pos;
            if (p  == 2) n4 = pos;
            nd[j] = (unsigned)min(n1 - pos, 255)
                  | ((unsigned)min(n2 - pos, 255) << 8)
                  | ((unsigned)min(n3 - pos, 255) << 16)
                  | ((unsigned)min(n4 - pos, 255) << 24);
        }
    }

    // ---------------- forward walk: FSM + factors + accumulate ----------------
    const int aT1 = pro[10], aT2 = pro[11], aP1 = pro[12], aP2 = pro[13];
    double sumAdj = 0.0;
    int vcount = 0;
    {
        int lT1 = exF[0], lT2 = exF[1], lP1 = exF[2], lP2 = exF[3], lV1 = exF[4], lV2 = exF[5];
        #pragma unroll
        for (int j = 0; j < PT; ++j) {
            const int nib = (int)((code >> (4*j)) & 0xFull);
            const int p = nib & 3, lc = (nib >> 2) & 3;
            const bool valid = lc != 3;
            const int pos = posBase + j;
            const int tm = (lT2 > lT1) ? 1 : 0;     // exclusive state
            const int pm = (lV2 > lV1) ? 1 : 0;
            float m = 1.0f;
            if (valid && p == 1 && pm == 0) m *= 100.0f;
            if (valid && p == 2 && pm == 1) m *= 100.0f;
            if (lc == 1 && tm == 1 && p == 1) m *= 0.1f;
            if (lc == 2 && tm == 0 && p == 2) m *= 0.1f;
            if (lc == 1) lT1 = pos;
            if (lc == 2) lT2 = pos;
            if (p  == 1) lP1 = pos;
            if (p  == 2) lP2 = pos;
            if (valid && p == 1) lV1 = pos;
            if (valid && p == 2) lV2 = pos;

            const int dpT1 = (lT1 >= 0) ? min(pos - lT1, 255) : 255;
            const int dpT2 = (lT2 >= 0) ? min(pos - lT2, 255) : 255;
            const int dpP1 = (lP1 >= 0) ? min(pos - lP1, 255) : 255;
            const int dpP2 = (lP2 >= 0) ? min(pos - lP2, 255) : 255;
            const unsigned ndj = nd[j];
            const int d2t1 = min(dpT1, (int)( ndj        & 255u));
            const int d2t2 = min(dpT2, (int)((ndj >> 8)  & 255u));
            const int d2p1 = min(dpP1, (int)((ndj >> 16) & 255u));
            const int d2p2 = min(dpP2, (int)((ndj >> 24) & 255u));

            if (p == 1) m *= aT1 ? ((d2t1 == 0) ? 0.1f : ((d2t1 <= 5) ? (0.1f + (float)d2t1 * 0.18f) : 10.0f)) : 20.0f;
            if (p == 2) m *= aT2 ? ((d2t2 == 0) ? 0.1f : ((d2t2 <= 5) ? (0.1f + (float)d2t2 * 0.18f) : 10.0f)) : 20.0f;
            if (lc == 1) m *= aP1 ? ((d2p1 > 5) ? fminf(2.0f + (float)(d2p1 - 5) * 0.3f, 8.0f) : 1.0f) : 5.0f;
            if (lc == 2) m *= aP2 ? ((d2p2 > 5) ? fminf(2.0f + (float)(d2p2 - 5) * 0.3f, 8.0f) : 1.0f) : 5.0f;

            sumAdj += (double)(ce[j] * m);
            vcount += valid ? 1 : 0;
        }
    }

    // ---------------- block reduce + last-block final ----------------
    double sA = sumAdj, sV = (double)vcount;
    #pragma unroll
    for (int o = 32; o > 0; o >>= 1) {
        sA += __shfl_down(sA, o);
        sV += __shfl_down(sV, o);
    }
    __shared__ double rr[2][4];
    __shared__ int isLast;
    if (lane == 0) { rr[0][wid] = sA; rr[1][wid] = sV; }
    __syncthreads();
    if (tid == 0) {
        const double a = rr[0][0] + rr[0][1] + rr[0][2] + rr[0][3];
        const double v = rr[1][0] + rr[1][1] + rr[1][2] + rr[1][3];
        __hip_atomic_store(&partials[2*chunkId+0], a, __ATOMIC_RELAXED, __HIP_MEMORY_SCOPE_AGENT);
        __hip_atomic_store(&partials[2*chunkId+1], v, __ATOMIC_RELAXED, __HIP_MEMORY_SCOPE_AGENT);
        const int old = __hip_atomic_fetch_add(ctr, 1, __ATOMIC_ACQ_REL, __HIP_MEMORY_SCOPE_AGENT);
        isLast = (old == NCH - 1) ? 1 : 0;
    }
    __syncthreads();
    if (isLast) {
        double tA = 0.0, tV = 0.0;
        for (int i = tid; i < NCH; i += NTHREADS) {
            tA += __hip_atomic_load(&partials[2*i+0], __ATOMIC_RELAXED, __HIP_MEMORY_SCOPE_AGENT);
            tV += __hip_atomic_load(&partials[2*i+1], __ATOMIC_RELAXED, __HIP_MEMORY_SCOPE_AGENT);
        }
        #pragma unroll
        for (int o = 32; o > 0; o >>= 1) {
            tA += __shfl_down(tA, o);
            tV += __shfl_down(tV, o);
        }
        __syncthreads();   // rr reuse safe after prior read
        if (lane == 0) { rr[0][wid] = tA; rr[1][wid] = tV; }
        __syncthreads();
        if (tid == 0) {
            const double A = rr[0][0] + rr[0][1] + rr[0][2] + rr[0][3];
            const double V = rr[1][0] + rr[1][1] + rr[1][2] + rr[1][3];
            out[0] = (float)(A / fmax(V, 1.0));
        }
    }
}

extern "C" void kernel_launch(void* const* d_in, const int* in_sizes, int n_in,
                              void* d_out, int out_size, void* d_ws, size_t ws_size,
                              hipStream_t stream) {
    const float* logits = (const float*)d_in[0];
    const int*   labels = (const int*)d_in[1];
    float* out = (float*)d_out;
    char* ws = (char*)d_ws;

    int*    flags = (int*)(ws + WS_FLAGS);
    int*    ctr   = (int*)(ws + WS_CTR);
    int*    sums  = (int*)(ws + WS_SUMS);
    double* parts = (double*)(ws + WS_PART);

    // stale flags/counter survive graph replays (ws not re-poisoned) -> wipe.
    hipMemsetAsync(ws, 0, WS_CLEAR, stream);
    fused_loss<<<NCH, NTHREADS, 0, stream>>>(logits, labels, flags, ctr, sums, parts, out);
}